// Round 4
// baseline (59.857 us; speedup 1.0000x reference)
//
#include <hip/hip_runtime.h>

// out[i,j] = exp((s1[i]-s2[j])^2) * gamma
// R4: fill-mimic write pattern. 256 blocks (1 per CU), each sweeps ONE
// contiguous 1 MB output region strictly sequentially. s1/s2 precomputed
// by a tiny rowsum kernel into d_ws. Each thread holds its 32 s2 values
// (8 column-chunks x 4) in registers; s1 is a wave-uniform scalar per row.

#define N1 8192
#define N2 8192
#define D  8
#define ROWS 32            // rows per block
#define NBLK (N1 / ROWS)   // 256 blocks

typedef float f32x4 __attribute__((ext_vector_type(4)));

__device__ __forceinline__ float rowsum8(const float* __restrict__ p) {
    const f32x4* q = reinterpret_cast<const f32x4*>(p);
    f32x4 a = q[0];
    f32x4 b = q[1];
    return ((a.x + a.y) + (a.z + a.w)) + ((b.x + b.y) + (b.z + b.w));
}

__global__ void rbf_rowsum_kernel(const float* __restrict__ in1,
                                  const float* __restrict__ in2,
                                  float* __restrict__ s) {
    int idx = blockIdx.x * blockDim.x + threadIdx.x;
    if (idx < N1) {
        s[idx] = rowsum8(in1 + (size_t)idx * D);
    } else if (idx < N1 + N2) {
        int j = idx - N1;
        s[N1 + j] = rowsum8(in2 + (size_t)j * D);
    }
}

__global__ void __launch_bounds__(256)
rbf_main_kernel(const float* __restrict__ s,
                const float* __restrict__ gamma_p,
                f32x4* __restrict__ out) {
    const int rb = blockIdx.x;       // row group: rows rb*32 .. rb*32+31
    const int t  = threadIdx.x;

    // Cache my 32 s2 values (8 chunks of 1024 cols; 4 cols each) in registers.
    const f32x4* s2v4 = reinterpret_cast<const f32x4*>(s + N1);
    f32x4 s2r[8];
    #pragma unroll
    for (int c = 0; c < 8; ++c) s2r[c] = s2v4[c * 256 + t];

    const float g = gamma_p[0];
    const float* s1p = s + rb * ROWS;

    // Block's output region: 1 MB contiguous, swept row by row.
    f32x4* __restrict__ obase = out + (size_t)rb * ROWS * (N2 / 4) + t;

    #pragma unroll 2
    for (int r = 0; r < ROWS; ++r) {
        const float s1 = s1p[r];               // wave-uniform scalar, L1/L2 hit
        f32x4* __restrict__ orow = obase + (size_t)r * (N2 / 4);
        #pragma unroll
        for (int c = 0; c < 8; ++c) {
            f32x4 sv = s2r[c];
            float d0 = s1 - sv.x;
            float d1 = s1 - sv.y;
            float d2 = s1 - sv.z;
            float d3 = s1 - sv.w;
            f32x4 v;
            v.x = __expf(d0 * d0) * g;
            v.y = __expf(d1 * d1) * g;
            v.z = __expf(d2 * d2) * g;
            v.w = __expf(d3 * d3) * g;
            __builtin_nontemporal_store(v, orow + c * 256);
        }
    }
}

extern "C" void kernel_launch(void* const* d_in, const int* in_sizes, int n_in,
                              void* d_out, int out_size, void* d_ws, size_t ws_size,
                              hipStream_t stream) {
    const float* in1     = (const float*)d_in[0];
    const float* in2     = (const float*)d_in[1];
    const float* gamma_p = (const float*)d_in[2];
    float* ws  = (float*)d_ws;                 // (N1+N2)*4 = 64 KB
    f32x4* out = (f32x4*)d_out;

    {
        const int threads = 256;
        const int blocks  = (N1 + N2 + threads - 1) / threads;
        rbf_rowsum_kernel<<<blocks, threads, 0, stream>>>(in1, in2, ws);
    }
    {
        rbf_main_kernel<<<NBLK, 256, 0, stream>>>(ws, gamma_p, out);
    }
}